// Round 6
// baseline (27.790 us; speedup 1.0000x reference)
//
#include <hip/hip_runtime.h>

// SWT-Haar level-1 MSE loss == plain MSE(x, target).
// Identity: with d = x-t, dr = roll(d,-1):
//   (cA_x-cA_t)^2 + (cD_x-cD_t)^2 = 0.5[(d+dr)^2 + (dr-d)^2] = d^2 + dr^2,
//   sum(dr^2) == sum(d^2) (circular shift is a permutation per row),
//   so mean over the 2N stacked coeffs = sum(d^2)/N = MSE(x, t).
//
// R5 post-mortem: same-address atomicAdd returns serialize at ~13 ns;
// 256-deep single-slot tail ~3.5 us. Fix: 2-level atomics -- 8 slots
// (one per XCD via default blockIdx%8 round-robin, each on its own 64B
// line, 32 contenders each in parallel) feeding 1 global slot (8 adds).
// Packed fixed-point u64 at both levels: value*2^22 in bits[12,63],
// arrival count in bits[0,11]. Integer adds commute => bit-deterministic.
// Overflow: leaf slot <= 32*2^50.6 ~ 2^55.6, global <= 2^58.6 < 2^63.

typedef float v4f __attribute__((ext_vector_type(4)));

#define NBLOCKS 256    // 1 block/CU
#define NTHREADS 1024  // 16 waves/CU
#define PAIRS 12       // n4 / (NBLOCKS*NTHREADS) for N = 16*3*512*512
#define FPS 4194304.0  // 2^22 fixed-point scale
#define NSLOTS 8       // one per XCD
#define SLOT_STRIDE 8  // u64s -> 64 B apart, no shared cache line

__global__ __launch_bounds__(NTHREADS)
void swt_mse_fused(const v4f* __restrict__ x, const v4f* __restrict__ t,
                   unsigned long long* __restrict__ slots,
                   float* __restrict__ out, int n4, double invN) {
    const int tid = blockIdx.x * NTHREADS + threadIdx.x;
    const int stride = NBLOCKS * NTHREADS;

    float acc = 0.0f;  // <=48 f32 terms/thread: accumulation error negligible
    if (n4 == PAIRS * stride) {
        // Exact-fit fast path: chunks of 4 pairs -> 8 dwordx4 loads batched.
        #pragma unroll
        for (int c = 0; c < PAIRS / 4; ++c) {
            v4f a0 = x[tid + (4 * c + 0) * stride];
            v4f a1 = x[tid + (4 * c + 1) * stride];
            v4f a2 = x[tid + (4 * c + 2) * stride];
            v4f a3 = x[tid + (4 * c + 3) * stride];
            v4f b0 = t[tid + (4 * c + 0) * stride];
            v4f b1 = t[tid + (4 * c + 1) * stride];
            v4f b2 = t[tid + (4 * c + 2) * stride];
            v4f b3 = t[tid + (4 * c + 3) * stride];
            v4f d0 = a0 - b0, d1 = a1 - b1, d2 = a2 - b2, d3 = a3 - b3;
            acc += d0.x * d0.x + d0.y * d0.y + d0.z * d0.z + d0.w * d0.w;
            acc += d1.x * d1.x + d1.y * d1.y + d1.z * d1.z + d1.w * d1.w;
            acc += d2.x * d2.x + d2.y * d2.y + d2.z * d2.z + d2.w * d2.w;
            acc += d3.x * d3.x + d3.y * d3.y + d3.z * d3.z + d3.w * d3.w;
        }
    } else {
        for (int i = tid; i < n4; i += stride) {
            v4f a = x[i], b = t[i];
            v4f d = a - b;
            acc += d.x * d.x + d.y * d.y + d.z * d.z + d.w * d.w;
        }
    }

    // wave64 butterfly reduce (double)
    double dacc = (double)acc;
    #pragma unroll
    for (int off = 32; off > 0; off >>= 1)
        dacc += __shfl_down(dacc, off, 64);

    __shared__ double sm[NTHREADS / 64];
    const int lane = threadIdx.x & 63;
    const int wid  = threadIdx.x >> 6;
    if (lane == 0) sm[wid] = dacc;
    __syncthreads();

    if (threadIdx.x == 0) {
        double s = 0.0;
        #pragma unroll
        for (int w = 0; w < NTHREADS / 64; ++w) s += sm[w];  // s >= 0
        // pack: fixed-point value in bits [12,63], arrival count in [0,11]
        unsigned long long packed =
            ((unsigned long long)(long long)(s * FPS + 0.5) << 12) | 1ull;
        const int slot = blockIdx.x & (NSLOTS - 1);  // same-XCD contenders
        unsigned long long old = atomicAdd(&slots[slot * SLOT_STRIDE], packed);
        if ((old & 0xFFFull) == (unsigned long long)(NBLOCKS / NSLOTS - 1)) {
            // last arrival in this slot: fold slot total into global slot
            unsigned long long slot_total = old + packed;
            unsigned long long gadd = (slot_total & ~0xFFFull) | 1ull;
            unsigned long long g =
                atomicAdd(&slots[NSLOTS * SLOT_STRIDE], gadd);
            if ((g & 0xFFFull) == (unsigned long long)(NSLOTS - 1)) {
                unsigned long long total = (g + gadd) >> 12;
                out[0] = (float)(((double)total / FPS) * invN);
            }
        }
    }
}

extern "C" void kernel_launch(void* const* d_in, const int* in_sizes, int n_in,
                              void* d_out, int out_size, void* d_ws, size_t ws_size,
                              hipStream_t stream) {
    const float* x = (const float*)d_in[0];
    const float* t = (const float*)d_in[1];
    float* out = (float*)d_out;
    unsigned long long* slots = (unsigned long long*)d_ws;

    long long N = (long long)in_sizes[0];   // 16*3*512*512 = 12,582,912
    int n4 = (int)(N / 4);                  // divisible by 4

    // zero 8 leaf slots (64B-strided) + 1 global slot: one 520 B memset node
    hipMemsetAsync(slots, 0, (NSLOTS * SLOT_STRIDE + 1) * sizeof(unsigned long long),
                   stream);
    swt_mse_fused<<<NBLOCKS, NTHREADS, 0, stream>>>(
        (const v4f*)x, (const v4f*)t, slots, out, n4, 1.0 / (double)N);
}

// Round 7
// 23.248 us; speedup vs baseline: 1.1954x; 1.1954x over previous
//
#include <hip/hip_runtime.h>

// SWT-Haar level-1 MSE loss == plain MSE(x, target).
// Identity: with d = x-t, dr = roll(d,-1):
//   (cA_x-cA_t)^2 + (cD_x-cD_t)^2 = 0.5[(d+dr)^2 + (dr-d)^2] = d^2 + dr^2,
//   sum(dr^2) == sum(d^2) (circular shift is a permutation per row),
//   so mean over the 2N stacked coeffs = sum(d^2)/N = MSE(x, t).
//
// R6 post-mortem: ALL single-kernel+memset+atomic variants (26-28 us) lose
// to the plain two-kernel structure (24.4 us) -- the memset node + atomic
// tail cost >= the second launch they replace. Reverting to two kernels
// (no atomics, no reset: every partial slot written unconditionally every
// call -> deterministic). One change vs round 1: compile-time exact-fit
// fully-unrolled load path so the compiler batches/pipelines up to 12
// independent dwordx4 loads per wave (round-1's runtime-trip rolled loop
// kept only ~2-4 in flight; at ~500cy HBM latency that caps BW well under
// peak).

typedef float v4f __attribute__((ext_vector_type(4)));

#define NBLOCKS 2048   // 8 blocks/CU x 256 CUs
#define NTHREADS 256
#define PAIRS 6        // n4 / (NBLOCKS*NTHREADS) for N = 16*3*512*512

__global__ __launch_bounds__(NTHREADS)
void swt_mse_partial(const v4f* __restrict__ x, const v4f* __restrict__ t,
                     double* __restrict__ part, int n4) {
    const int tid = blockIdx.x * NTHREADS + threadIdx.x;
    const int stride = NBLOCKS * NTHREADS;

    float acc = 0.0f;  // <=24 f32 terms/thread: accumulation error negligible
    if (n4 == PAIRS * stride) {
        // Exact-fit path: compile-time trip count; compiler hoists the 12
        // independent dwordx4 loads for deep memory-level parallelism.
        #pragma unroll
        for (int k = 0; k < PAIRS; ++k) {
            v4f a = x[tid + k * stride];
            v4f b = t[tid + k * stride];
            v4f d = a - b;
            acc += d.x * d.x + d.y * d.y + d.z * d.z + d.w * d.w;
        }
    } else {
        for (int i = tid; i < n4; i += stride) {
            v4f a = x[i], b = t[i];
            v4f d = a - b;
            acc += d.x * d.x + d.y * d.y + d.z * d.z + d.w * d.w;
        }
    }

    // wave64 butterfly reduce (double)
    double dacc = (double)acc;
    #pragma unroll
    for (int off = 32; off > 0; off >>= 1)
        dacc += __shfl_down(dacc, off, 64);

    __shared__ double sm[NTHREADS / 64];
    const int lane = threadIdx.x & 63;
    const int wid  = threadIdx.x >> 6;
    if (lane == 0) sm[wid] = dacc;
    __syncthreads();
    if (threadIdx.x == 0) {
        double s = 0.0;
        #pragma unroll
        for (int w = 0; w < NTHREADS / 64; ++w) s += sm[w];
        part[blockIdx.x] = s;  // every slot written every call -> deterministic
    }
}

__global__ __launch_bounds__(256)
void swt_mse_final(const double* __restrict__ part, float* __restrict__ out,
                   double invN) {
    double acc = 0.0;
    #pragma unroll
    for (int k = 0; k < NBLOCKS / 256; ++k)
        acc += part[threadIdx.x + k * 256];
    #pragma unroll
    for (int off = 32; off > 0; off >>= 1)
        acc += __shfl_down(acc, off, 64);

    __shared__ double sm[4];
    const int lane = threadIdx.x & 63;
    const int wid  = threadIdx.x >> 6;
    if (lane == 0) sm[wid] = acc;
    __syncthreads();
    if (threadIdx.x == 0)
        out[0] = (float)((sm[0] + sm[1] + sm[2] + sm[3]) * invN);
}

extern "C" void kernel_launch(void* const* d_in, const int* in_sizes, int n_in,
                              void* d_out, int out_size, void* d_ws, size_t ws_size,
                              hipStream_t stream) {
    const float* x = (const float*)d_in[0];
    const float* t = (const float*)d_in[1];
    float* out = (float*)d_out;
    double* part = (double*)d_ws;  // 2048 * 8 B = 16 KB scratch

    long long N = (long long)in_sizes[0];   // 16*3*512*512 = 12,582,912
    int n4 = (int)(N / 4);                  // divisible by 4

    swt_mse_partial<<<NBLOCKS, NTHREADS, 0, stream>>>(
        (const v4f*)x, (const v4f*)t, part, n4);
    swt_mse_final<<<1, 256, 0, stream>>>(part, out, 1.0 / (double)N);
}